// Round 5
// baseline (786.779 us; speedup 1.0000x reference)
//
#include <hip/hip_runtime.h>
#include <cstdint>
#include <cstddef>

typedef unsigned int  uint_t;
typedef unsigned short ushort_t;

// ---- shapes (fixed for this problem) ----
constexpr int B_  = 64;
constexpr int S_  = 128;
constexpr int D_  = 100;   // triple embedding dim
constexpr int E_  = 300;   // word embedding dim
constexpr int H_  = 256;   // hidden
constexpr int KIN = 512;   // LSTM input 500 padded to 512 for MFMA K
constexpr int NG  = 1024;  // 4*H gates
constexpr int M_  = B_ * S_;  // 8192

// K3: quad (4 lanes) owns one hidden unit; each thread owns a K-quarter
// (32 f16x2 words per gate row). Per row: RW2 words in VGPRs, LW2 in LDS.
constexpr int RW2 = 24;
constexpr int LW2 = 8;

// ---- workspace layout (bytes) ----
constexpr size_t OFF_WT   = 0;                                  // W_ent^T bf16 [200][100]  (40000 B)
constexpr size_t OFF_FLAG = 40000;                              // int: 1 if inputs are fp32, 0 if bf16
constexpr size_t OFF_WIH  = 40960;                              // W_ih padded bf16 [1024][512]
constexpr size_t OFF_WHH  = OFF_WIH + (size_t)NG * KIN * 2;     // W_hh as f16x2, [128][1024] u32
constexpr size_t OFF_TIN  = OFF_WHH + (size_t)128 * NG * 4;     // t_in bf16 [8192][512]
constexpr size_t OFF_XG   = OFF_TIN + (size_t)M_ * KIN * 2;     // xg f32 [8192][1024]
constexpr size_t OFF_HOUT = OFF_XG + (size_t)M_ * NG * 4;       // h f32 [8192][256]
// total ~50 MB

// ---- helpers ----
__device__ __forceinline__ float b2f(ushort_t u) {
  union { uint_t u; float f; } v; v.u = ((uint_t)u) << 16; return v.f;
}
__device__ __forceinline__ float blo(uint_t u) {
  union { uint_t u; float f; } v; v.u = u << 16; return v.f;
}
__device__ __forceinline__ float bhi(uint_t u) {
  union { uint_t u; float f; } v; v.u = u & 0xffff0000u; return v.f;
}
__device__ __forceinline__ ushort_t f2b(float f) {  // RNE float->bf16
  union { float f; uint_t u; } v; v.f = f;
  uint_t r = (v.u + 0x7fffu + ((v.u >> 16) & 1u)) >> 16;
  return (ushort_t)r;
}
__device__ __forceinline__ ushort_t f16bits(float f) {
  _Float16 h = (_Float16)f;
  union { _Float16 h; ushort_t u; } v; v.h = h; return v.u;
}
__device__ __forceinline__ float fast_tanh(float x) {
  float e = __expf(2.f * x);
  return 1.f - 2.f / (e + 1.f);
}
__device__ __forceinline__ float sigm(float x) {
  return 1.f / (1.f + __expf(-x));
}
// dtype-flexible load of an external "float" tensor
__device__ __forceinline__ float ldv(const void* p, size_t i, int f32) {
  return f32 ? ((const float*)p)[i] : b2f(((const ushort_t*)p)[i]);
}

#if defined(__has_builtin)
#if __has_builtin(__builtin_amdgcn_fdot2)
#define HAVE_FDOT2 1
#endif
#endif

typedef _Float16 half2v __attribute__((ext_vector_type(2)));

__device__ __forceinline__ float dot2(uint_t w, uint_t h, float acc) {
#ifdef HAVE_FDOT2
  union { uint_t u; half2v v; } a, b; a.u = w; b.u = h;
  return __builtin_amdgcn_fdot2(a.v, b.v, acc, false);
#else
  union { uint_t u; _Float16 h[2]; } a, b; a.u = w; b.u = h;
  acc += (float)a.h[0] * (float)b.h[0];
  acc += (float)a.h[1] * (float)b.h[1];
  return acc;
#endif
}

// =====================================================================
// K_detect: decide whether external float tensors are fp32 or bf16.
// =====================================================================
__global__ __launch_bounds__(64) void k_detect(const uint_t* __restrict__ emb_w,
                                               char* __restrict__ ws)
{
  int tid = threadIdx.x;
  int hits = 0;
  for (int i = 0; i < 8; ++i) {
    uint_t w = emb_w[i * 64 + tid];
    uint_t e = (w >> 7) & 0xffu;   // exponent field of lo-ushort-as-bf16
    hits += (e >= 140) ? 1 : 0;
  }
  for (int off = 32; off > 0; off >>= 1) hits += __shfl_down(hits, off);
  if (tid == 0) *(int*)(ws + OFF_FLAG) = (hits >= 32) ? 1 : 0;
}

// =====================================================================
// K0: weight prep. Wt = W_ent^T (bf16); W_ih padded K 500->512 (bf16);
// W_hh -> f16x2 packed, transposed to [kpair][row].
// =====================================================================
__global__ __launch_bounds__(256) void k0_prep(
    const void* __restrict__ W_ent, const void* __restrict__ W_ih,
    const void* __restrict__ W_hh, char* __restrict__ ws)
{
  const int f32 = *(const int*)(ws + OFF_FLAG);
  int id = blockIdx.x * 256 + threadIdx.x;
  ushort_t* Wt = (ushort_t*)(ws + OFF_WT);
  ushort_t* Wp = (ushort_t*)(ws + OFF_WIH);
  uint_t*   WT = (uint_t*)(ws + OFF_WHH);
  if (id < 20000) {
    int k = id / 100, d = id % 100;
    Wt[id] = f2b(ldv(W_ent, (size_t)d * 200 + k, f32));   // Wt[k][d] = W_ent[d][k]
  } else if (id < 20000 + NG * KIN) {
    int i = id - 20000;
    int n = i >> 9, k = i & 511;
    Wp[i] = (k < 500) ? f2b(ldv(W_ih, (size_t)n * 500 + k, f32)) : (ushort_t)0;
  } else if (id < 20000 + NG * KIN + 128 * NG) {
    int i = id - 20000 - NG * KIN;
    int kk = i >> 10, j = i & 1023;
    ushort_t lo = f16bits(ldv(W_hh, (size_t)j * 256 + 2 * kk,     f32));
    ushort_t hi = f16bits(ldv(W_hh, (size_t)j * 256 + 2 * kk + 1, f32));
    WT[kk * 1024 + j] = (uint_t)lo | ((uint_t)hi << 16);
  }
}

// =====================================================================
// K1: triple graph attention per (b,s); writes t_in bf16 [m][512].
// =====================================================================
__global__ __launch_bounds__(128) void k1_graph(
    const int* __restrict__ inputs, const int* __restrict__ triples,
    const int* __restrict__ id2, const void* __restrict__ emb,
    const void* __restrict__ ent, const void* __restrict__ rel,
    char* __restrict__ ws)
{
  __shared__ __align__(16) ushort_t Wl[20000];   // W^T [k][d], 40000 B
  __shared__ float ht_l[10][200];
  __shared__ float er_l[10][100];
  __shared__ float e_l[10];
  __shared__ float alpha_l[10];
  __shared__ int   trip_l[30];
  __shared__ int   vflag;

  const int tid = threadIdx.x;
  const int m   = blockIdx.x;  // b*128+s
  const int f32 = *(const int*)(ws + OFF_FLAG);
  const ushort_t* Wt = (const ushort_t*)(ws + OFF_WT);
  ushort_t* tin = (ushort_t*)(ws + OFF_TIN);

  if (tid < 30) trip_l[tid] = triples[(size_t)m * 30 + tid];
  if (tid == 0) vflag = 0;
  if (tid < 10) e_l[tid] = 0.f;
  __syncthreads();
  if (tid < 10 && id2[(size_t)m * 10 + tid] != -1) atomicOr(&vflag, 1);

  {
    const uint4* src = (const uint4*)Wt;
    uint4* dst = (uint4*)Wl;
    for (int i = tid; i < 2500; i += 128) dst[i] = src[i];
  }
  for (int i = tid; i < 2000; i += 128) {
    int t = i / 200, k = i % 200;
    int row = trip_l[t * 3 + (k < 100 ? 0 : 1)];
    int kk = (k < 100) ? k : k - 100;
    ht_l[t][k] = ldv(ent, (size_t)row * 100 + kk, f32);
  }
  for (int i = tid; i < 1000; i += 128) {
    int t = i / 100, d = i % 100;
    er_l[t][d] = ldv(rel, (size_t)trip_l[t * 3 + 2] * 100 + d, f32);
  }
  {
    int w = inputs[m];
    for (int c = tid; c < 300; c += 128)
      tin[(size_t)m * KIN + c] = f2b(ldv(emb, (size_t)w * E_ + c, f32));
    if (tid < 12) tin[(size_t)m * KIN + 500 + tid] = 0;
  }
  __syncthreads();

  if (tid < 125) {
    int t2 = tid / 25, d4 = tid % 25;
    int t0 = 2 * t2, t1 = t0 + 1;
    float a00 = 0, a01 = 0, a02 = 0, a03 = 0;
    float a10 = 0, a11 = 0, a12 = 0, a13 = 0;
    for (int k = 0; k < 200; ++k) {
      uint2 wu = *(const uint2*)&Wl[k * 100 + 4 * d4];
      float h0 = ht_l[t0][k], h1 = ht_l[t1][k];
      float w0 = blo(wu.x), w1 = bhi(wu.x), w2 = blo(wu.y), w3 = bhi(wu.y);
      a00 += w0 * h0; a01 += w1 * h0; a02 += w2 * h0; a03 += w3 * h0;
      a10 += w0 * h1; a11 += w1 * h1; a12 += w2 * h1; a13 += w3 * h1;
    }
    int d = 4 * d4;
    float s0 = fast_tanh(a00) * er_l[t0][d]     + fast_tanh(a01) * er_l[t0][d + 1]
             + fast_tanh(a02) * er_l[t0][d + 2] + fast_tanh(a03) * er_l[t0][d + 3];
    float s1 = fast_tanh(a10) * er_l[t1][d]     + fast_tanh(a11) * er_l[t1][d + 1]
             + fast_tanh(a12) * er_l[t1][d + 2] + fast_tanh(a13) * er_l[t1][d + 3];
    atomicAdd(&e_l[t0], s0);
    atomicAdd(&e_l[t1], s1);
  }
  __syncthreads();
  if (tid == 0) {
    float mx = e_l[0];
    for (int t = 1; t < 10; ++t) mx = fmaxf(mx, e_l[t]);
    float s = 0.f;
    for (int t = 0; t < 10; ++t) { float v = __expf(e_l[t] - mx); alpha_l[t] = v; s += v; }
    float inv = 1.f / s;
    for (int t = 0; t < 10; ++t) alpha_l[t] *= inv;
  }
  __syncthreads();
  for (int k2 = tid; k2 < 200; k2 += 128) {
    float g = 0.f;
#pragma unroll
    for (int t = 0; t < 10; ++t) g += alpha_l[t] * ht_l[t][k2];
    if (!vflag) g = 0.f;
    tin[(size_t)m * KIN + 300 + k2] = f2b(g);
  }
}

// =====================================================================
// K2: xg = t_in @ W_ih^T + b.  MFMA 16x16x32 bf16, 128x128 tiles, BK=32.
// =====================================================================
typedef __attribute__((ext_vector_type(8))) short short8;
typedef __attribute__((ext_vector_type(4))) float f32x4;

__global__ __launch_bounds__(256) void k2_xg(
    const void* __restrict__ bl, char* __restrict__ ws)
{
  __shared__ __align__(16) ushort_t As[128 * 32];
  __shared__ __align__(16) ushort_t Bs[128 * 32];
  const ushort_t* A  = (const ushort_t*)(ws + OFF_TIN);
  const ushort_t* Bw = (const ushort_t*)(ws + OFF_WIH);
  float* xg = (float*)(ws + OFF_XG);
  const int f32 = *(const int*)(ws + OFF_FLAG);

  const int tid = threadIdx.x;
  const int m0 = blockIdx.x * 128;
  const int n0 = blockIdx.y * 128;
  const int lane = tid & 63, wv = tid >> 6;
  const int wm = wv & 1, wn = wv >> 1;
  const int g = lane >> 4, r = lane & 15;

  f32x4 acc[4][4] = {};

  for (int ks = 0; ks < 16; ++ks) {
    const int k0 = ks * 32;
    {
      int c0 = tid, c1 = tid + 256;
      uint4 a0 = *(const uint4*)(A  + (size_t)(m0 + (c0 >> 2)) * KIN + k0 + ((c0 & 3) << 3));
      uint4 a1 = *(const uint4*)(A  + (size_t)(m0 + (c1 >> 2)) * KIN + k0 + ((c1 & 3) << 3));
      uint4 b0 = *(const uint4*)(Bw + (size_t)(n0 + (c0 >> 2)) * KIN + k0 + ((c0 & 3) << 3));
      uint4 b1 = *(const uint4*)(Bw + (size_t)(n0 + (c1 >> 2)) * KIN + k0 + ((c1 & 3) << 3));
      ((uint4*)As)[c0] = a0; ((uint4*)As)[c1] = a1;
      ((uint4*)Bs)[c0] = b0; ((uint4*)Bs)[c1] = b1;
    }
    __syncthreads();
    short8 av[4], bv[4];
#pragma unroll
    for (int i = 0; i < 4; ++i)
      av[i] = *(const short8*)&As[(wm * 64 + i * 16 + r) * 32 + g * 8];
#pragma unroll
    for (int j = 0; j < 4; ++j)
      bv[j] = *(const short8*)&Bs[(wn * 64 + j * 16 + r) * 32 + g * 8];
#pragma unroll
    for (int i = 0; i < 4; ++i)
#pragma unroll
      for (int j = 0; j < 4; ++j)
        acc[i][j] = __builtin_amdgcn_mfma_f32_16x16x32_bf16(av[i], bv[j], acc[i][j], 0, 0, 0);
    __syncthreads();
  }
#pragma unroll
  for (int j = 0; j < 4; ++j) {
    int n = n0 + wn * 64 + j * 16 + r;
    float bias = ldv(bl, n, f32);
#pragma unroll
    for (int i = 0; i < 4; ++i) {
      int mrow = m0 + wm * 64 + i * 16 + g * 4;
#pragma unroll
      for (int rr = 0; rr < 4; ++rr)
        xg[(size_t)(mrow + rr) * NG + n] = acc[i][j][rr] + bias;
    }
  }
}

// =====================================================================
// K3: recurrent LSTM + fused attention/logits epilogue.
// 64 blocks (1/batch) x 1024 threads (16 waves = 4/SIMD -> hard 128-VGPR
// cap, which the allocator prefers anyway; weight array sized to FIT it).
// Quad of lanes (tid&3) owns hidden unit u=tid>>2, all 4 gate rows
// {u,u+256,u+512,u+768}; each thread owns K-quarter words [32q,32q+32).
// Per row: RW2=24 words in VGPRs (96 total), LW2=8 in LDS
// ([chunk][tid] uint4, conflict-free b128; 128 KB). h double-buffered
// in LDS as f16; one barrier/step; quad combine via shfl_xor 1,2.
// LDS-part dots process one row at a time to keep live temps minimal.
// =====================================================================
__global__ __attribute__((amdgpu_waves_per_eu(4, 4))) __launch_bounds__(1024)
void k3_lstm(const int* __restrict__ lengths, const void* __restrict__ attn_w,
             const void* __restrict__ attn_b, const void* __restrict__ out_w,
             const void* __restrict__ out_b, char* __restrict__ ws,
             void* __restrict__ out)
{
  extern __shared__ __align__(16) char smem[];
  uint4*    ldsw = (uint4*)smem;                         // [8][1024] uint4 = 128 KB
  ushort_t* hbuf = (ushort_t*)(smem + 8 * 1024 * 16);    // [2][256] f16

  const int tid = threadIdx.x;
  const int b   = blockIdx.x;
  const int u   = tid >> 2;        // hidden unit 0..255
  const int q   = tid & 3;         // K-quarter
  const int kbase = q * 32;        // first f16x2 word of my K-slice

  const uint_t* WT = (const uint_t*)(ws + OFF_WHH);  // [kpair][1024]
  const float* xg = (const float*)(ws + OFF_XG);
  float* hout = (float*)(ws + OFF_HOUT);

  const int row0 = u, row1 = u + 256, row2 = u + 512, row3 = u + 768;

  // ---- register-resident weights: 4 rows x RW2 words = 96 VGPRs
  uint_t w0[RW2], w1[RW2], w2[RW2], w3[RW2];
#pragma unroll
  for (int j = 0; j < RW2; ++j) {
    w0[j] = WT[(size_t)(kbase + j) * 1024 + row0];
    w1[j] = WT[(size_t)(kbase + j) * 1024 + row1];
    w2[j] = WT[(size_t)(kbase + j) * 1024 + row2];
    w3[j] = WT[(size_t)(kbase + j) * 1024 + row3];
  }
  // ---- LDS-resident weights: chunk c=i*2+p holds words kbase+RW2+4p..+3 of row i
  {
    const int rows[4] = { row0, row1, row2, row3 };
#pragma unroll
    for (int i = 0; i < 4; ++i)
#pragma unroll
      for (int p = 0; p < 2; ++p) {
        uint4 v;
        v.x = WT[(size_t)(kbase + RW2 + 4 * p + 0) * 1024 + rows[i]];
        v.y = WT[(size_t)(kbase + RW2 + 4 * p + 1) * 1024 + rows[i]];
        v.z = WT[(size_t)(kbase + RW2 + 4 * p + 2) * 1024 + rows[i]];
        v.w = WT[(size_t)(kbase + RW2 + 4 * p + 3) * 1024 + rows[i]];
        ldsw[(i * 2 + p) * 1024 + tid] = v;
      }
  }
  if (tid < 512) hbuf[tid] = 0;   // zero both h buffers
  float c = 0.f;
  __syncthreads();

  const int bm = b * S_;
  for (int t = 0; t < S_; ++t) {
    const int cur = t & 1;
    // gate inputs: issued now, consumed after dots (latency hidden)
    const float* xp = xg + (size_t)(bm + t) * NG;
    float x0 = xp[row0], x1 = xp[row1], x2 = xp[row2], x3 = xp[row3];

    const uint4* hb4 = (const uint4*)(hbuf + cur * 256);
    float a0 = 0.f, a1 = 0.f, a2 = 0.f, a3 = 0.f;
    // register part: 6 uint4 h-reads x 16 dot2
#pragma unroll
    for (int r = 0; r < RW2 / 4; ++r) {
      uint4 hv = hb4[q * 8 + r];
      a0 = dot2(w0[4 * r], hv.x, a0); a0 = dot2(w0[4 * r + 1], hv.y, a0);
      a0 = dot2(w0[4 * r + 2], hv.z, a0); a0 = dot2(w0[4 * r + 3], hv.w, a0);
      a1 = dot2(w1[4 * r], hv.x, a1); a1 = dot2(w1[4 * r + 1], hv.y, a1);
      a1 = dot2(w1[4 * r + 2], hv.z, a1); a1 = dot2(w1[4 * r + 3], hv.w, a1);
      a2 = dot2(w2[4 * r], hv.x, a2); a2 = dot2(w2[4 * r + 1], hv.y, a2);
      a2 = dot2(w2[4 * r + 2], hv.z, a2); a2 = dot2(w2[4 * r + 3], hv.w, a2);
      a3 = dot2(w3[4 * r], hv.x, a3); a3 = dot2(w3[4 * r + 1], hv.y, a3);
      a3 = dot2(w3[4 * r + 2], hv.z, a3); a3 = dot2(w3[4 * r + 3], hv.w, a3);
    }
    // LDS part: one row at a time (minimal live temps)
#pragma unroll
    for (int p = 0; p < 2; ++p) {
      uint4 hv = hb4[q * 8 + 6 + p];
      {
        uint4 v = ldsw[(0 * 2 + p) * 1024 + tid];
        a0 = dot2(v.x, hv.x, a0); a0 = dot2(v.y, hv.y, a0);
        a0 = dot2(v.z, hv.z, a0); a0 = dot2(v.w, hv.w, a0);
      }
      {
        uint4 v = ldsw[(1 * 2 + p) * 1024 + tid];
        a1 = dot2(v.x, hv.x, a1); a1 = dot2(v.y, hv.y, a1);
        a1 = dot2(v.z, hv.z, a1); a1 = dot2(v.w, hv.w, a1);
      }
      {
        uint4 v = ldsw[(2 * 2 + p) * 1024 + tid];
        a2 = dot2(v.x, hv.x, a2); a2 = dot2(v.y, hv.y, a2);
        a2 = dot2(v.z, hv.z, a2); a2 = dot2(v.w, hv.w, a2);
      }
      {
        uint4 v = ldsw[(3 * 2 + p) * 1024 + tid];
        a3 = dot2(v.x, hv.x, a3); a3 = dot2(v.y, hv.y, a3);
        a3 = dot2(v.z, hv.z, a3); a3 = dot2(v.w, hv.w, a3);
      }
    }
    // combine K-quarters across the quad
    a0 += __shfl_xor(a0, 1); a0 += __shfl_xor(a0, 2);
    a1 += __shfl_xor(a1, 1); a1 += __shfl_xor(a1, 2);
    a2 += __shfl_xor(a2, 1); a2 += __shfl_xor(a2, 2);
    a3 += __shfl_xor(a3, 1); a3 += __shfl_xor(a3, 2);
    float gi = a0 + x0, gf = a1 + x1, gg = a2 + x2, go = a3 + x3;
    c = sigm(gf) * c + sigm(gi) * fast_tanh(gg);
    float hv_ = sigm(go) * fast_tanh(c);
    if (q == 0) {
      hout[(size_t)(bm + t) * H_ + u] = hv_;
      hbuf[(cur ^ 1) * 256 + u] = f16bits(hv_);
    }
    __syncthreads();
  }

  // ================= fused attention pooling + logits =================
  const int f32 = *(const int*)(ws + OFF_FLAG);
  float* aw  = (float*)smem;         // 256 f32
  float* sc  = aw + 256;             // 128 f32
  float* at  = sc + 128;             // 256 f32
  float* red = at + 256;             // 256 f32
  __syncthreads();                   // weights region dead; reuse smem

  if (tid < 256) aw[tid] = ldv(attn_w, tid, f32);
  __syncthreads();
  if (tid < 128) {
    const float* hp = hout + (size_t)(bm + tid) * H_;
    float acc = 0.f;
    for (int k = 0; k < 256; k += 4) {
      float4 h4 = *(const float4*)(hp + k);
      acc += h4.x * aw[k] + h4.y * aw[k + 1] + h4.z * aw[k + 2] + h4.w * aw[k + 3];
    }
    sc[tid] = acc + ldv(attn_b, 0, f32);
  }
  __syncthreads();
  if (tid == 0) {
    int len = lengths[b];
    float mx = -3.4e38f;
    for (int s = 0; s < len; ++s) mx = fmaxf(mx, sc[s]);
    float sum = 0.f;
    for (int s = 0; s < 128; ++s) {
      float v = (s < len) ? __expf(sc[s] - mx) : 0.f;
      sc[s] = v; sum += v;
    }
    float inv = 1.f / sum;
    for (int s = 0; s < 128; ++s) sc[s] *= inv;
  }
  __syncthreads();
  if (tid < 256) {
    float acc = 0.f;
    for (int s = 0; s < 128; ++s)
      acc += sc[s] * hout[(size_t)(bm + s) * H_ + tid];
    at[tid] = acc;
  }
  __syncthreads();
  for (int cc = 0; cc < 3; ++cc) {
    if (tid < 256) red[tid] = at[tid] * ldv(out_w, cc * 256 + tid, f32);
    __syncthreads();
    for (int off = 128; off > 0; off >>= 1) {
      if (tid < off) red[tid] += red[tid + off];
      __syncthreads();
    }
    if (tid == 0) {
      float v = red[0] + ldv(out_b, cc, f32);
      if (f32) ((float*)out)[b * 3 + cc] = v;
      else     ((ushort_t*)out)[b * 3 + cc] = f2b(v);
    }
    __syncthreads();
  }
}

// =====================================================================
extern "C" void kernel_launch(void* const* d_in, const int* in_sizes, int n_in,
                              void* d_out, int out_size, void* d_ws, size_t ws_size,
                              hipStream_t stream)
{
  const int* inputs  = (const int*)d_in[0];
  const int* triples = (const int*)d_in[2];
  const int* lengths = (const int*)d_in[3];
  const int* id2     = (const int*)d_in[4];
  const void* emb    = d_in[5];
  const void* ent    = d_in[6];
  const void* rel    = d_in[7];
  const void* W_ent  = d_in[8];
  const void* W_ih   = d_in[9];
  const void* W_hh   = d_in[10];
  const void* b_lstm = d_in[11];
  const void* attn_w = d_in[12];
  const void* attn_b = d_in[13];
  const void* out_w  = d_in[14];
  const void* out_b  = d_in[15];
  char* ws = (char*)d_ws;

  constexpr int K3_SMEM = 8 * 1024 * 16 + 2 * 256 * 2;  // 132096 B
  static bool attr_set = false;
  if (!attr_set) {
    (void)hipFuncSetAttribute((const void*)k3_lstm,
                              hipFuncAttributeMaxDynamicSharedMemorySize, K3_SMEM);
    attr_set = true;
  }

  k_detect<<<dim3(1), dim3(64), 0, stream>>>((const uint_t*)emb, ws);
  k0_prep<<<dim3(2639), dim3(256), 0, stream>>>(W_ent, W_ih, W_hh, ws);
  k1_graph<<<dim3(M_), dim3(128), 0, stream>>>(inputs, triples, id2, emb, ent, rel, ws);
  k2_xg<<<dim3(64, 8), dim3(256), 0, stream>>>(b_lstm, ws);
  k3_lstm<<<dim3(B_), dim3(1024), K3_SMEM, stream>>>(lengths, attn_w, attn_b,
                                                     out_w, out_b, ws, d_out);
}